// Round 9
// baseline (27.197 us; speedup 1.0000x reference)
//
#include <hip/hip_runtime.h>

// Problem constants (match reference: B=8192, S=7, C=30)
#define YB      8192
#define YS      7
#define YC      30
#define NCELLS  (YB * YS * YS)        // 401408
#define TCELLS  32                    // cells per wave-tile
#define TBYTES  (TCELLS * YC * 4)     // 3840 B per array per tile
#define TFLOATS (TCELLS * YC)         // 960 floats
#define NTILES  (NCELLS / TCELLS)     // 12544, divides exactly
#define BLOCK   256
#define GRID    1280                  // 5 blocks/CU exactly (30.7 KB LDS each)
#define NWAVES  (GRID * 4)            // 5120 waves, 2-3 tiles each

__device__ __forceinline__ float iou_quirk(float cx1, float cy1, float w1, float h1,
                                           float cx2, float cy2, float w2, float h2) {
    // Faithful replica of reference _iou, including inter/area1 + area2 - inter quirk.
    float area1 = w1 * h1;
    float area2 = w2 * h2;
    float max_left   = fmaxf(cx1 - w1 * 0.5f, cx2 - w2 * 0.5f);
    float min_right  = fminf(cx1 + w1 * 0.5f, cx2 + w2 * 0.5f);
    float max_top    = fmaxf(cy1 - h1 * 0.5f, cy2 - h2 * 0.5f);
    float min_bottom = fminf(cy1 + h1 * 0.5f, cy2 + h2 * 0.5f);
    float inter = (min_right - max_left) * (min_bottom - max_top);
    bool overlap = (max_left < min_right) && (max_top < min_bottom);
    return overlap ? (inter / area1 + area2 - inter) : 0.0f;
}

// Per-lane cell loss from a staged 32-cell LDS tile (lanes >= TCELLS contribute 0).
__device__ __forceinline__ float cell_loss(const float* __restrict__ sp,
                                           const float* __restrict__ sl, int lane) {
    if (lane >= TCELLS) return 0.0f;
    // Cell base = lane*120 B (8B-aligned) -> float2. Stride 30 floats -> 2-way
    // bank alias per wave = free (m136).
    const float2* p2 = (const float2*)(sp + lane * YC);
    const float2* l2 = (const float2*)(sl + lane * YC);

    float pv[10], lv[10];
    #pragma unroll
    for (int i = 0; i < 5; ++i) {
        float2 a = p2[i]; pv[2 * i] = a.x; pv[2 * i + 1] = a.y;
        float2 b = l2[i]; lv[2 * i] = b.x; lv[2 * i + 1] = b.y;
    }
    float loss_cls = 0.0f;
    #pragma unroll
    for (int i = 5; i < 15; ++i) {
        float2 a = p2[i], b = l2[i];
        float dx = a.x - b.x, dy = a.y - b.y;
        loss_cls += dx * dx + dy * dy;
    }

    float iou1 = iou_quirk(pv[0], pv[1], pv[2], pv[3], lv[0], lv[1], lv[2], lv[3]);
    float iou2 = iou_quirk(pv[5], pv[6], pv[7], pv[8], lv[5], lv[6], lv[7], lv[8]);
    bool resp1 = iou1 > iou2;

    float dx1 = pv[0] - lv[0], dy1 = pv[1] - lv[1];
    float xy1 = dx1 * dx1 + dy1 * dy1;
    float dx2 = pv[5] - lv[5], dy2 = pv[6] - lv[6];
    float xy2 = dx2 * dx2 + dy2 * dy2;

    float sw1 = sqrtf(pv[2]) - sqrtf(lv[2]), sh1 = sqrtf(pv[3]) - sqrtf(lv[3]);
    float wh1 = sw1 * sw1 + sh1 * sh1;
    float sw2 = sqrtf(pv[7]) - sqrtf(lv[7]), sh2 = sqrtf(pv[8]) - sqrtf(lv[8]);
    float wh2 = sw2 * sw2 + sh2 * sh2;

    float d1 = pv[4] - iou1, d2 = pv[9] - iou2;
    float e1 = d1 * d1, e2 = d2 * d2;

    float obj_cell = 5.0f * (resp1 ? xy1 : xy2)
                   + (resp1 ? wh1 : wh2)
                   + (resp1 ? e1 : e2)
                   + 0.5f * (resp1 ? e2 : e1)
                   + loss_cls;
    float noobj_cell = 0.5f * (pv[4] * pv[4] + pv[9] * pv[9]);

    // labels[...,4] is exactly 0.0 or 1.0
    return (lv[4] == 1.0f) ? obj_cell : noobj_cell;
}

__global__ __launch_bounds__(BLOCK) void yolo_partial_kernel(const float* __restrict__ preds,
                                                             const float* __restrict__ labels,
                                                             float* __restrict__ partial) {
    // Per-wave private single-buffered tile, register-prefetched (T14 split).
    // [wave][array][floats] = 4*2*960*4 = 30720 B -> 5 blocks/CU, 20 waves/CU.
    // NO __syncthreads anywhere; same-wave DS ops are in-order, so
    // ds_write(tile t) then ds_read(tile t) then ds_write(tile t+1) is safe.
    __shared__ float lds[4][2][TFLOATS];

    const int tid  = threadIdx.x;
    const int lane = tid & 63;
    const int w    = tid >> 6;
    const int gw   = blockIdx.x * 4 + w;   // global wave id, < NWAVES <= NTILES

    float* sp = &lds[w][0][0];
    float* sl = &lds[w][1][0];

    // Register staging: per lane 3840 B/array = 3x float4 + 1x float2 + 1x float,
    // all rounds coalesced (lane-contiguous), zero divergence, exact coverage.
    float4 rp0, rp1, rp2; float2 rp3; float rp4;
    float4 rl0, rl1, rl2; float2 rl3; float rl4;

    #define LOAD_TILE(t)                                                      \
        do {                                                                  \
            const char* gp_ = (const char*)preds  + (size_t)(t) * TBYTES;     \
            const char* gl_ = (const char*)labels + (size_t)(t) * TBYTES;     \
            rp0 = *(const float4*)(gp_ +    0 + lane * 16);                   \
            rp1 = *(const float4*)(gp_ + 1024 + lane * 16);                   \
            rp2 = *(const float4*)(gp_ + 2048 + lane * 16);                   \
            rp3 = *(const float2*)(gp_ + 3072 + lane *  8);                   \
            rp4 = *(const float*) (gp_ + 3584 + lane *  4);                   \
            rl0 = *(const float4*)(gl_ +    0 + lane * 16);                   \
            rl1 = *(const float4*)(gl_ + 1024 + lane * 16);                   \
            rl2 = *(const float4*)(gl_ + 2048 + lane * 16);                   \
            rl3 = *(const float2*)(gl_ + 3072 + lane *  8);                   \
            rl4 = *(const float*) (gl_ + 3584 + lane *  4);                   \
        } while (0)

    #define WRITE_TILE()                                                      \
        do {                                                                  \
            *(float4*)((char*)sp +    0 + lane * 16) = rp0;                   \
            *(float4*)((char*)sp + 1024 + lane * 16) = rp1;                   \
            *(float4*)((char*)sp + 2048 + lane * 16) = rp2;                   \
            *(float2*)((char*)sp + 3072 + lane *  8) = rp3;                   \
            *(float*) ((char*)sp + 3584 + lane *  4) = rp4;                   \
            *(float4*)((char*)sl +    0 + lane * 16) = rl0;                   \
            *(float4*)((char*)sl + 1024 + lane * 16) = rl1;                   \
            *(float4*)((char*)sl + 2048 + lane * 16) = rl2;                   \
            *(float2*)((char*)sl + 3072 + lane *  8) = rl3;                   \
            *(float*) ((char*)sl + 3584 + lane *  4) = rl4;                   \
        } while (0)

    float acc = 0.0f;

    int t = gw;                         // every wave has at least 2 tiles
    LOAD_TILE(t);
    for (;;) {
        const int tn = t + NWAVES;
        WRITE_TILE();                   // compiler waits vmcnt for reg use here
        if (tn < NTILES) LOAD_TILE(tn); // issue next-tile loads (wave-uniform branch)
        __builtin_amdgcn_sched_barrier(0);   // pin load issue above the compute
        acc += cell_loss(sp, sl, lane);      // ds_read after ds_write: in-order DS
        if (tn >= NTILES) break;
        t = tn;
    }

    #undef LOAD_TILE
    #undef WRITE_TILE

    // Deterministic wave64 shuffle-tree reduction; one partial per wave.
    for (int off = 32; off > 0; off >>= 1) acc += __shfl_down(acc, off);
    if (lane == 0) partial[gw] = acc;
}

__global__ __launch_bounds__(BLOCK) void yolo_final_kernel(const float* __restrict__ partial,
                                                           float* __restrict__ out) {
    __shared__ double w[BLOCK / 64];
    double s = 0.0;
    for (int i = threadIdx.x; i < NWAVES; i += BLOCK) s += (double)partial[i];
    for (int off = 32; off > 0; off >>= 1) s += __shfl_down(s, off);
    const int lane = threadIdx.x & 63, wid = threadIdx.x >> 6;
    if (lane == 0) w[wid] = s;
    __syncthreads();
    if (threadIdx.x == 0) out[0] = (float)((w[0] + w[1] + w[2] + w[3]) / (double)YB);
}

extern "C" void kernel_launch(void* const* d_in, const int* in_sizes, int n_in,
                              void* d_out, int out_size, void* d_ws, size_t ws_size,
                              hipStream_t stream) {
    const float* preds  = (const float*)d_in[0];
    const float* labels = (const float*)d_in[1];
    float* out = (float*)d_out;
    float* partial = (float*)d_ws;   // needs NWAVES*4 = 20480 bytes

    yolo_partial_kernel<<<GRID, BLOCK, 0, stream>>>(preds, labels, partial);
    yolo_final_kernel<<<1, BLOCK, 0, stream>>>(partial, out);
}